// Round 6
// baseline (1420.412 us; speedup 1.0000x reference)
//
#include <hip/hip_runtime.h>

#define N_ 128
#define T_ 128
#define V_ 25
#define TV 3200
#define LL 3
#define SS 5
#define II 16
#define EPSB 1e-5f
#define MCNT 409600.0f

// stats float2 slots: c1:[0,48) c2:[48,288) new:[288,352) y:[352,416) t:[416,448) p:[448,464)

__device__ __forceinline__ float2 bncoef(const float2* st, int slot, float g, float bt){
  float2 s = st[slot];
  float m  = s.x * (1.0f/MCNT);
  float var = s.y * (1.0f/MCNT) - m*m;
  float a = g * rsqrtf(var + EPSB);
  return make_float2(a, bt - m*a);
}

// ---------------- K1: c1[l] = x * gdw[l]^T + gdb[l]  (48 out channels), + stats ----------------
__global__ __launch_bounds__(256) void k1_conv_dw(
    const float* __restrict__ x, const float* __restrict__ gdw, const float* __restrict__ gdb,
    float* __restrict__ c1, float2* st)
{
  __shared__ float w[64*48];      // w[c*48+o] = gdw[o*64+c]
  __shared__ float bias[48];
  __shared__ float bst[4][96];
  const int tid = threadIdx.x;
  for (int i = tid; i < 64*48; i += 256){ int c = i/48, o = i - c*48; w[i] = gdw[o*64 + c]; }
  if (tid < 48) bias[tid] = gdb[tid];
  __syncthreads();
  const int n = blockIdx.y;
  const int rem = blockIdx.x*256 + tid;
  const bool act = rem < TV;
  float acc[48];
  #pragma unroll
  for (int o = 0; o < 48; o++) acc[o] = act ? bias[o] : 0.f;
  const float* xp = x + (size_t)n*64*TV + rem;
  if (act){
    #pragma unroll 4
    for (int c = 0; c < 64; c++){
      float xv = xp[c*TV];
      const float4* w4 = (const float4*)&w[c*48];
      #pragma unroll
      for (int o4 = 0; o4 < 12; o4++){
        float4 ww = w4[o4];
        acc[o4*4+0] += ww.x*xv; acc[o4*4+1] += ww.y*xv;
        acc[o4*4+2] += ww.z*xv; acc[o4*4+3] += ww.w*xv;
      }
    }
    #pragma unroll
    for (int o = 0; o < 48; o++){
      int l = o >> 4, oi = o & 15;
      c1[(size_t)((l*N_+n)*II + oi)*TV + rem] = acc[o];
    }
  }
  const int wv = tid >> 6, lane = tid & 63;
  #pragma unroll
  for (int o = 0; o < 48; o++){
    float s = acc[o], q = acc[o]*acc[o];
    #pragma unroll
    for (int m = 32; m; m >>= 1){ s += __shfl_xor(s, m); q += __shfl_xor(q, m); }
    if (lane == 0){ bst[wv][2*o] = s; bst[wv][2*o+1] = q; }
  }
  __syncthreads();
  float* stf = (float*)st;
  if (tid < 96) unsafeAtomicAdd(stf + tid, bst[0][tid]+bst[1][tid]+bst[2][tid]+bst[3][tid]);
}

// ---------------- K2: c2 stats via SGPR-pa scheme ----------------
// Lane = (t2 = lane>>4, oc = lane&15); wave w handles v = w + 4i (wave-uniform v).
// pa rows are wave-uniform -> s_load into SGPRs, consumed as the scalar operand of v_fmac.
// xd in per-lane VGPRs; only the 16-wide c-reduction goes through LDS (zz), same-wave
// write->read (v uniform), so NO barriers in the j loop. LDS ops per wave per j: ~35 vs 88.
__global__ __launch_bounds__(256) void k2_spatial_stats(
    const float* __restrict__ c1, const float* __restrict__ PA,
    const float* __restrict__ gsw, const float* __restrict__ gsb,
    const float* __restrict__ gdg, const float* __restrict__ gdbt,
    float2* st)
{
  __shared__ float zz[4][25][16];
  __shared__ float bst[4][160];
  const int tid = threadIdx.x;
  const int l = blockIdx.z, n = blockIdx.y;
  const int wu = __builtin_amdgcn_readfirstlane(tid >> 6);  // wave id in SGPR
  const int lane = tid & 63;
  const int t2 = lane >> 4, oc = lane & 15;
  const int t = blockIdx.x*4 + t2;
  // BN(c1) coefs for this lane's oc
  float cAr, cBr;
  {
    float2 s = st[l*16+oc];
    float m = s.x*(1.f/MCNT), var = s.y*(1.f/MCNT) - m*m;
    cAr = gdg[l*16+oc]*rsqrtf(var+EPSB);
    cBr = gdbt[l*16+oc] - m*cAr;
  }
  // xd row for (n, oc, t): 25 contiguous floats
  float xdr[25];
  {
    const float* c1p = c1 + ((size_t)((l*N_+n)*II + oc))*TV + t*25;
    #pragma unroll
    for (int u = 0; u < 25; u++) xdr[u] = fmaxf(cAr*c1p[u] + cBr, 0.f);
  }
  #pragma unroll 1
  for (int j = 0; j < 5; j++){
    const float* paJ = PA + (size_t)(l*5+j)*625;
    const float* gwp = gsw + ((size_t)((l*5+j)*16 + oc))*16;
    float gwr[16];
    #pragma unroll
    for (int c4 = 0; c4 < 4; c4++){
      float4 g4 = *(const float4*)(gwp + 4*c4);
      gwr[4*c4+0]=g4.x; gwr[4*c4+1]=g4.y; gwr[4*c4+2]=g4.z; gwr[4*c4+3]=g4.w;
    }
    const float bjo = gsb[(l*5+j)*16 + oc];
    float ssum = 0.f, sq = 0.f;
    #pragma unroll
    for (int i = 0; i < 7; i++){
      const int vreal = wu + 4*i;
      const int v = vreal < 25 ? vreal : 24;      // clamp: loads always in-bounds
      const float* par = paJ + v*25;
      float pan[25];
      #pragma unroll
      for (int u = 0; u < 25; u++) pan[u] = par[u];   // uniform -> SGPRs
      if (vreal < 25){                                 // wave-uniform guard
        float z0 = xdr[0]*pan[0], z1 = xdr[1]*pan[1], z2 = xdr[2]*pan[2], z3 = xdr[3]*pan[3];
        #pragma unroll
        for (int u = 4; u < 24; u += 4){
          z0 += xdr[u+0]*pan[u+0];
          z1 += xdr[u+1]*pan[u+1];
          z2 += xdr[u+2]*pan[u+2];
          z3 += xdr[u+3]*pan[u+3];
        }
        z0 += xdr[24]*pan[24];
        zz[t2][v][oc] = (z0+z1)+(z2+z3);
        // conv: same-wave RAW on zz row v (in-order DS) — no barrier
        const float4* zr = (const float4*)&zz[t2][v][0];
        float4 za = zr[0], zb = zr[1], zc = zr[2], zd = zr[3];
        float d0 = gwr[0]*za.x + gwr[1]*za.y + gwr[2]*za.z + gwr[3]*za.w;
        float d1 = gwr[4]*zb.x + gwr[5]*zb.y + gwr[6]*zb.z + gwr[7]*zb.w;
        float d2 = gwr[8]*zc.x + gwr[9]*zc.y + gwr[10]*zc.z + gwr[11]*zc.w;
        float d3 = gwr[12]*zd.x + gwr[13]*zd.y + gwr[14]*zd.z + gwr[15]*zd.w;
        float cv = bjo + ((d0+d1)+(d2+d3));
        ssum += cv; sq += cv*cv;
      }
    }
    // reduce over t2 groups (lanes differing in bits 4,5)
    ssum += __shfl_xor(ssum,16); ssum += __shfl_xor(ssum,32);
    sq   += __shfl_xor(sq,16);   sq   += __shfl_xor(sq,32);
    if (t2 == 0){ bst[wu][2*(j*16+oc)] = ssum; bst[wu][2*(j*16+oc)+1] = sq; }
  }
  __syncthreads();
  float* stf = (float*)st;
  for (int i = tid; i < 160; i += 256)
    unsafeAtomicAdd(stf + 96 + l*160 + i, bst[0][i]+bst[1][i]+bst[2][i]+bst[3][i]);
}

// ---------------- K3: recompute c2, BN, accumulate new = sum_l(ys[j]+ys[0]), stats(new) ----
// Same SGPR-pa scheme as K2. Accumulators: 5 statically-named arrays indexed by unrolled i,
// selected by wave-uniform branch on runtime j (rule #20: no runtime-indexed register arrays).
__global__ __launch_bounds__(256) void k3_new(
    const float* __restrict__ c1, const float* __restrict__ PA,
    const float* __restrict__ gsw, const float* __restrict__ gsb,
    const float* __restrict__ gdg, const float* __restrict__ gdbt,
    const float* __restrict__ gsg, const float* __restrict__ gsbt,
    float2* st, float* __restrict__ newb)
{
  __shared__ float zz[4][25][16];
  __shared__ float bst[4][128];
  const int tid = threadIdx.x;
  const int n = blockIdx.y;
  const int wu = __builtin_amdgcn_readfirstlane(tid >> 6);
  const int lane = tid & 63;
  const int t2 = lane >> 4, oc = lane & 15;
  const int t = blockIdx.x*4 + t2;
  float base[7], ac1[7], ac2[7], ac3[7], ac4[7];
  #pragma unroll
  for (int i = 0; i < 7; i++){ base[i]=0.f; ac1[i]=0.f; ac2[i]=0.f; ac3[i]=0.f; ac4[i]=0.f; }

  #pragma unroll 1
  for (int l = 0; l < 3; l++){
    float cAr, cBr;
    {
      float2 s = st[l*16+oc];
      float m = s.x*(1.f/MCNT), var = s.y*(1.f/MCNT) - m*m;
      cAr = gdg[l*16+oc]*rsqrtf(var+EPSB);
      cBr = gdbt[l*16+oc] - m*cAr;
    }
    float xdr[25];
    {
      const float* c1p = c1 + ((size_t)((l*N_+n)*II + oc))*TV + t*25;
      #pragma unroll
      for (int u = 0; u < 25; u++) xdr[u] = fmaxf(cAr*c1p[u] + cBr, 0.f);
    }
    #pragma unroll 1
    for (int j = 0; j < 5; j++){
      const float* paJ = PA + (size_t)(l*5+j)*625;
      const float* gwp = gsw + ((size_t)((l*5+j)*16 + oc))*16;
      float gwr[16];
      #pragma unroll
      for (int c4 = 0; c4 < 4; c4++){
        float4 g4 = *(const float4*)(gwp + 4*c4);
        gwr[4*c4+0]=g4.x; gwr[4*c4+1]=g4.y; gwr[4*c4+2]=g4.z; gwr[4*c4+3]=g4.w;
      }
      const float bjo = gsb[(l*5+j)*16 + oc];
      float a2, b2;   // BN(c2) coefs for (l,j,oc)
      {
        int slot = 48 + (l*5+j)*16 + oc;
        float2 s = st[slot];
        float m = s.x*(1.f/MCNT), var = s.y*(1.f/MCNT) - m*m;
        a2 = gsg[(l*5+j)*16+oc]*rsqrtf(var+EPSB);
        b2 = gsbt[(l*5+j)*16+oc] - m*a2;
      }
      float yb_[7];
      #pragma unroll
      for (int i = 0; i < 7; i++){
        const int vreal = wu + 4*i;
        const int v = vreal < 25 ? vreal : 24;
        const float* par = paJ + v*25;
        float pan[25];
        #pragma unroll
        for (int u = 0; u < 25; u++) pan[u] = par[u];
        yb_[i] = 0.f;
        if (vreal < 25){
          float z0 = xdr[0]*pan[0], z1 = xdr[1]*pan[1], z2 = xdr[2]*pan[2], z3 = xdr[3]*pan[3];
          #pragma unroll
          for (int u = 4; u < 24; u += 4){
            z0 += xdr[u+0]*pan[u+0];
            z1 += xdr[u+1]*pan[u+1];
            z2 += xdr[u+2]*pan[u+2];
            z3 += xdr[u+3]*pan[u+3];
          }
          z0 += xdr[24]*pan[24];
          zz[t2][v][oc] = (z0+z1)+(z2+z3);
          const float4* zr = (const float4*)&zz[t2][v][0];
          float4 za = zr[0], zb = zr[1], zc = zr[2], zd = zr[3];
          float d0 = gwr[0]*za.x + gwr[1]*za.y + gwr[2]*za.z + gwr[3]*za.w;
          float d1 = gwr[4]*zb.x + gwr[5]*zb.y + gwr[6]*zb.z + gwr[7]*zb.w;
          float d2 = gwr[8]*zc.x + gwr[9]*zc.y + gwr[10]*zc.z + gwr[11]*zc.w;
          float d3 = gwr[12]*zd.x + gwr[13]*zd.y + gwr[14]*zd.z + gwr[15]*zd.w;
          yb_[i] = a2*(bjo + ((d0+d1)+(d2+d3))) + b2;
        }
      }
      // wave-uniform select on runtime j; all register indices static
      if (j == 0){
        #pragma unroll
        for (int i = 0; i < 7; i++) base[i] += yb_[i];
      } else if (j == 1){
        #pragma unroll
        for (int i = 0; i < 7; i++) ac1[i] += yb_[i];
      } else if (j == 2){
        #pragma unroll
        for (int i = 0; i < 7; i++) ac2[i] += yb_[i];
      } else if (j == 3){
        #pragma unroll
        for (int i = 0; i < 7; i++) ac3[i] += yb_[i];
      } else {
        #pragma unroll
        for (int i = 0; i < 7; i++) ac4[i] += yb_[i];
      }
    }
  }
  // new[g] = acc[g+1] + base ; write + stats
  float* np = newb + (size_t)n*64*TV + t*25;
  float s0=0.f,q0=0.f,s1=0.f,q1=0.f,s2=0.f,q2=0.f,s3=0.f,q3=0.f;
  #pragma unroll
  for (int i = 0; i < 7; i++){
    const int v = wu + 4*i;
    if (v < 25){
      float v0 = ac1[i] + base[i];
      float v1 = ac2[i] + base[i];
      float v2 = ac3[i] + base[i];
      float v3 = ac4[i] + base[i];
      np[(0*16+oc)*TV + v] = v0;
      np[(1*16+oc)*TV + v] = v1;
      np[(2*16+oc)*TV + v] = v2;
      np[(3*16+oc)*TV + v] = v3;
      s0 += v0; q0 += v0*v0;
      s1 += v1; q1 += v1*v1;
      s2 += v2; q2 += v2*v2;
      s3 += v3; q3 += v3*v3;
    }
  }
  s0 += __shfl_xor(s0,16); s0 += __shfl_xor(s0,32);
  q0 += __shfl_xor(q0,16); q0 += __shfl_xor(q0,32);
  s1 += __shfl_xor(s1,16); s1 += __shfl_xor(s1,32);
  q1 += __shfl_xor(q1,16); q1 += __shfl_xor(q1,32);
  s2 += __shfl_xor(s2,16); s2 += __shfl_xor(s2,32);
  q2 += __shfl_xor(q2,16); q2 += __shfl_xor(q2,32);
  s3 += __shfl_xor(s3,16); s3 += __shfl_xor(s3,32);
  q3 += __shfl_xor(q3,16); q3 += __shfl_xor(q3,32);
  if (t2 == 0){
    bst[wu][2*(0*16+oc)] = s0; bst[wu][2*(0*16+oc)+1] = q0;
    bst[wu][2*(1*16+oc)] = s1; bst[wu][2*(1*16+oc)+1] = q1;
    bst[wu][2*(2*16+oc)] = s2; bst[wu][2*(2*16+oc)+1] = q2;
    bst[wu][2*(3*16+oc)] = s3; bst[wu][2*(3*16+oc)+1] = q3;
  }
  __syncthreads();
  float* stf = (float*)st;
  for (int i = tid; i < 128; i += 256)
    unsafeAtomicAdd(stf + 576 + i, bst[0][i]+bst[1][i]+bst[2][i]+bst[3][i]);
}

// ---------------- K4: xg = relu(bn(new)+x); y[k] = brw[k]*xg + brb[k]; stats(y) ----------------
__global__ __launch_bounds__(256) void k4_xg_branches(
    const float* __restrict__ x, const float* __restrict__ newb,
    const float* __restrict__ gbng, const float* __restrict__ gbnb,
    const float* __restrict__ brw, const float* __restrict__ brb,
    float2* st, float* __restrict__ xg, float* __restrict__ y)
{
  __shared__ float w[64*64];     // w[c*64+ko] = brw[ko*64+c]
  __shared__ float cA[64], cB[64], bias[64];
  __shared__ float bst[4][128];
  const int tid = threadIdx.x;
  for (int i = tid; i < 4096; i += 256){ int c = i >> 6, ko = i & 63; w[i] = brw[ko*64 + c]; }
  if (tid < 64){
    float2 ab = bncoef(st, 288+tid, gbng[tid], gbnb[tid]);
    cA[tid] = ab.x; cB[tid] = ab.y; bias[tid] = brb[tid];
  }
  __syncthreads();
  const int n = blockIdx.y;
  const int rem = blockIdx.x*256 + tid;
  const bool act = rem < TV;
  const float* xp  = x    + (size_t)n*64*TV + rem;
  const float* npx = newb + (size_t)n*64*TV + rem;
  float*       xgp = xg   + (size_t)n*64*TV + rem;
  float xgv[64];
  #pragma unroll
  for (int c = 0; c < 64; c++){
    float v = 0.f;
    if (act){
      v = fmaxf(cA[c]*npx[c*TV] + cB[c] + xp[c*TV], 0.f);
      xgp[c*TV] = v;
    }
    xgv[c] = v;
  }
  const int wv = tid >> 6, lane = tid & 63;
  #pragma unroll
  for (int k = 0; k < 4; k++){
    float acc[16];
    #pragma unroll
    for (int o = 0; o < 16; o++) acc[o] = act ? bias[k*16+o] : 0.f;
    #pragma unroll
    for (int c = 0; c < 64; c++){
      float xv = xgv[c];
      const float4* w4 = (const float4*)&w[c*64 + k*16];
      #pragma unroll
      for (int o4 = 0; o4 < 4; o4++){
        float4 ww = w4[o4];
        acc[o4*4+0] += ww.x*xv; acc[o4*4+1] += ww.y*xv;
        acc[o4*4+2] += ww.z*xv; acc[o4*4+3] += ww.w*xv;
      }
    }
    if (act){
      float* yp = y + (size_t)((k*N_+n)*16)*TV + rem;
      #pragma unroll
      for (int o = 0; o < 16; o++) yp[o*TV] = acc[o];
    }
    #pragma unroll
    for (int o = 0; o < 16; o++){
      float s = acc[o], q = acc[o]*acc[o];
      #pragma unroll
      for (int m = 32; m; m >>= 1){ s += __shfl_xor(s, m); q += __shfl_xor(q, m); }
      if (lane == 0){ bst[wv][2*(k*16+o)] = s; bst[wv][2*(k*16+o)+1] = q; }
    }
  }
  __syncthreads();
  float* stf = (float*)st;
  for (int i = tid; i < 128; i += 256)
    unsafeAtomicAdd(stf + 704 + i, bst[0][i]+bst[1][i]+bst[2][i]+bst[3][i]);
}

// ---------------- K5: temporal convs (d=1,2) + maxpool branch, pre-final-BN values + stats -----
__global__ __launch_bounds__(256) void k5_temporal(
    const float* __restrict__ y, const float* __restrict__ tcw, const float* __restrict__ tcbias,
    const float* __restrict__ brg, const float* __restrict__ brbt,
    float2* st, float* __restrict__ tp)
{
  __shared__ float wt[2*16*5*16];   // [k][c][ks][o]
  __shared__ float cAy[48], cBy[48];
  __shared__ float bst[4][96];
  const int tid = threadIdx.x;
  for (int i = tid; i < 2560; i += 256){
    int k = i/1280, r = i - k*1280, c = r/80, r2 = r - c*80, ks = r2 >> 4, o = r2 & 15;
    wt[i] = tcw[((k*16+o)*16 + c)*5 + ks];
  }
  if (tid < 48){
    float2 ab = bncoef(st, 352+tid, brg[tid], brbt[tid]);
    cAy[tid] = ab.x; cBy[tid] = ab.y;
  }
  __syncthreads();
  const int n = blockIdx.y;
  const int rem = blockIdx.x*256 + tid;
  const bool act = rem < TV;
  const int t = rem/25, v = rem - t*25;
  const int wv = tid >> 6, lane = tid & 63;
  #pragma unroll
  for (int k = 0; k < 2; k++){
    const int d = k + 1;
    float acc[16];
    #pragma unroll
    for (int o = 0; o < 16; o++) acc[o] = act ? tcbias[k*16+o] : 0.f;
    if (act){
      const float* yp = y + (size_t)((k*N_+n)*16)*TV;
      #pragma unroll
      for (int ks = 0; ks < 5; ks++){
        int ttt = t + d*(ks-2);
        if (ttt >= 0 && ttt < T_){
          int off = ttt*25 + v;
          #pragma unroll
          for (int c = 0; c < 16; c++){
            float val = fmaxf(cAy[k*16+c]*yp[c*TV + off] + cBy[k*16+c], 0.f);
            const float4* w4 = (const float4*)&wt[((k*16+c)*5 + ks)*16];
            #pragma unroll
            for (int o4 = 0; o4 < 4; o4++){
              float4 ww = w4[o4];
              acc[o4*4+0] += ww.x*val; acc[o4*4+1] += ww.y*val;
              acc[o4*4+2] += ww.z*val; acc[o4*4+3] += ww.w*val;
            }
          }
        }
      }
      float* op = tp + (size_t)k*6553600 + (size_t)(n*16)*TV + rem;
      #pragma unroll
      for (int o = 0; o < 16; o++) op[o*TV] = acc[o];
    }
    #pragma unroll
    for (int o = 0; o < 16; o++){
      float s = acc[o], q = acc[o]*acc[o];
      #pragma unroll
      for (int m = 32; m; m >>= 1){ s += __shfl_xor(s, m); q += __shfl_xor(q, m); }
      if (lane == 0){ bst[wv][2*(k*16+o)] = s; bst[wv][2*(k*16+o)+1] = q; }
    }
  }
  { // maxpool branch (k=2)
    float mx[16];
    #pragma unroll
    for (int o = 0; o < 16; o++) mx[o] = -1e30f;
    if (act){
      const float* yp = y + (size_t)((2*N_+n)*16)*TV;
      #pragma unroll
      for (int dt = -1; dt <= 1; dt++){
        int ttt = t + dt;
        if (ttt >= 0 && ttt < T_){
          int off = ttt*25 + v;
          #pragma unroll
          for (int o = 0; o < 16; o++){
            float val = fmaxf(cAy[32+o]*yp[o*TV + off] + cBy[32+o], 0.f);
            mx[o] = fmaxf(mx[o], val);
          }
        }
      }
      float* op = tp + (size_t)2*6553600 + (size_t)(n*16)*TV + rem;
      #pragma unroll
      for (int o = 0; o < 16; o++) op[o*TV] = mx[o];
    } else {
      #pragma unroll
      for (int o = 0; o < 16; o++) mx[o] = 0.f;
    }
    #pragma unroll
    for (int o = 0; o < 16; o++){
      float s = mx[o], q = mx[o]*mx[o];
      #pragma unroll
      for (int m = 32; m; m >>= 1){ s += __shfl_xor(s, m); q += __shfl_xor(q, m); }
      if (lane == 0){ bst[wv][64 + 2*o] = s; bst[wv][64 + 2*o + 1] = q; }
    }
  }
  __syncthreads();
  float* stf = (float*)st;
  for (int i = tid; i < 96; i += 256)
    unsafeAtomicAdd(stf + 832 + i, bst[0][i]+bst[1][i]+bst[2][i]+bst[3][i]);
}

// ---------------- K6: final BNs + concat + residual + relu ----------------
__global__ __launch_bounds__(256) void k6_final(
    const float* __restrict__ tp, const float* __restrict__ y, const float* __restrict__ xg,
    const float* __restrict__ tcg, const float* __restrict__ tcbt,
    const float* __restrict__ mpg, const float* __restrict__ mpb,
    const float* __restrict__ brg, const float* __restrict__ brbt,
    const float2* __restrict__ st, float* __restrict__ out)
{
  __shared__ float cA[64], cB[64];
  const int tid = threadIdx.x;
  if (tid < 64){
    int o = tid & 15;
    float2 ab;
    if (tid < 32)      ab = bncoef(st, 416 + tid, tcg[tid], tcbt[tid]);
    else if (tid < 48) ab = bncoef(st, 448 + o, mpg[o], mpb[o]);
    else               ab = bncoef(st, 400 + o, brg[48+o], brbt[48+o]);
    cA[tid] = ab.x; cB[tid] = ab.y;
  }
  __syncthreads();
  const int n = blockIdx.y;
  const int rem = blockIdx.x*256 + tid;
  if (rem >= TV) return;
  const float* xgp = xg + (size_t)n*64*TV + rem;
  float* op = out + (size_t)n*64*TV + rem;
  #pragma unroll
  for (int ch = 0; ch < 64; ch++){
    int o = ch & 15;
    float sv;
    if (ch < 48) sv = tp[(size_t)(ch>>4)*6553600 + (size_t)(n*16+o)*TV + rem];
    else         sv = y[(size_t)((3*N_+n)*16 + o)*TV + rem];
    float val = cA[ch]*sv + cB[ch] + xgp[ch*TV];
    op[ch*TV] = fmaxf(val, 0.f);
  }
}

extern "C" void kernel_launch(void* const* d_in, const int* in_sizes, int n_in,
                              void* d_out, int out_size, void* d_ws, size_t ws_size,
                              hipStream_t stream) {
  (void)in_sizes; (void)n_in; (void)out_size; (void)ws_size;
  const float* x    = (const float*)d_in[0];
  const float* PA   = (const float*)d_in[1];
  const float* gdw  = (const float*)d_in[2];
  const float* gdb  = (const float*)d_in[3];
  const float* gdg  = (const float*)d_in[4];
  const float* gdbt = (const float*)d_in[5];
  const float* gsw  = (const float*)d_in[6];
  const float* gsb  = (const float*)d_in[7];
  const float* gsg  = (const float*)d_in[8];
  const float* gsbt = (const float*)d_in[9];
  const float* gbng = (const float*)d_in[10];
  const float* gbnb = (const float*)d_in[11];
  const float* brw  = (const float*)d_in[12];
  const float* brb  = (const float*)d_in[13];
  const float* brg  = (const float*)d_in[14];
  const float* brbt = (const float*)d_in[15];
  const float* tcw  = (const float*)d_in[16];
  const float* tcbias=(const float*)d_in[17];
  const float* tcg  = (const float*)d_in[18];
  const float* tcbt = (const float*)d_in[19];
  const float* mpg  = (const float*)d_in[20];
  const float* mpb  = (const float*)d_in[21];

  char* ws = (char*)d_ws;
  float2* st  = (float2*)ws;                                   // 4 KB stats
  float* c1   = (float*)(ws + 4096);                           // 78.6 MB (reused as tp later)
  float* tp   = c1;
  float* newb = (float*)(ws + 4096 + 78643200);                // 104.9 MB
  float* xg   = (float*)(ws + 4096 + 78643200 + 104857600);    // 104.9 MB
  float* y    = (float*)(ws + 4096 + 78643200 + 209715200);    // 104.9 MB

  hipMemsetAsync(st, 0, 4096, stream);
  dim3 b(256);
  k1_conv_dw     <<<dim3(13,128),   b, 0, stream>>>(x, gdw, gdb, c1, st);
  k2_spatial_stats<<<dim3(32,128,3), b, 0, stream>>>(c1, PA, gsw, gsb, gdg, gdbt, st);
  k3_new         <<<dim3(32,128),   b, 0, stream>>>(c1, PA, gsw, gsb, gdg, gdbt, gsg, gsbt, st, newb);
  k4_xg_branches <<<dim3(13,128),   b, 0, stream>>>(x, newb, gbng, gbnb, brw, brb, st, xg, y);
  k5_temporal    <<<dim3(13,128),   b, 0, stream>>>(y, tcw, tcbias, brg, brbt, st, tp);
  k6_final       <<<dim3(13,128),   b, 0, stream>>>(tp, y, xg, tcg, tcbt, mpg, mpb, brg, brbt, st, (float*)d_out);
}

// Round 7
// 1306.764 us; speedup vs baseline: 1.0870x; 1.0870x over previous
//
#include <hip/hip_runtime.h>

#define N_ 128
#define T_ 128
#define V_ 25
#define TV 3200
#define LL 3
#define SS 5
#define II 16
#define EPSB 1e-5f
#define MCNT 409600.0f

// stats float2 slots: c1:[0,48) c2:[48,288) new:[288,352) y:[352,416) t:[416,448) p:[448,464)

__device__ __forceinline__ float2 bncoef(const float2* st, int slot, float g, float bt){
  float2 s = st[slot];
  float m  = s.x * (1.0f/MCNT);
  float var = s.y * (1.0f/MCNT) - m*m;
  float a = g * rsqrtf(var + EPSB);
  return make_float2(a, bt - m*a);
}

// ---------------- K1: c1[l] = x * gdw[l]^T + gdb[l]  (48 out channels), + stats ----------------
__global__ __launch_bounds__(256) void k1_conv_dw(
    const float* __restrict__ x, const float* __restrict__ gdw, const float* __restrict__ gdb,
    float* __restrict__ c1, float2* st)
{
  __shared__ float w[64*48];      // w[c*48+o] = gdw[o*64+c]
  __shared__ float bias[48];
  __shared__ float bst[4][96];
  const int tid = threadIdx.x;
  for (int i = tid; i < 64*48; i += 256){ int c = i/48, o = i - c*48; w[i] = gdw[o*64 + c]; }
  if (tid < 48) bias[tid] = gdb[tid];
  __syncthreads();
  const int n = blockIdx.y;
  const int rem = blockIdx.x*256 + tid;
  const bool act = rem < TV;
  float acc[48];
  #pragma unroll
  for (int o = 0; o < 48; o++) acc[o] = act ? bias[o] : 0.f;
  const float* xp = x + (size_t)n*64*TV + rem;
  if (act){
    #pragma unroll 4
    for (int c = 0; c < 64; c++){
      float xv = xp[c*TV];
      const float4* w4 = (const float4*)&w[c*48];
      #pragma unroll
      for (int o4 = 0; o4 < 12; o4++){
        float4 ww = w4[o4];
        acc[o4*4+0] += ww.x*xv; acc[o4*4+1] += ww.y*xv;
        acc[o4*4+2] += ww.z*xv; acc[o4*4+3] += ww.w*xv;
      }
    }
    #pragma unroll
    for (int o = 0; o < 48; o++){
      int l = o >> 4, oi = o & 15;
      c1[(size_t)((l*N_+n)*II + oi)*TV + rem] = acc[o];
    }
  }
  const int wv = tid >> 6, lane = tid & 63;
  #pragma unroll
  for (int o = 0; o < 48; o++){
    float s = acc[o], q = acc[o]*acc[o];
    #pragma unroll
    for (int m = 32; m; m >>= 1){ s += __shfl_xor(s, m); q += __shfl_xor(q, m); }
    if (lane == 0){ bst[wv][2*o] = s; bst[wv][2*o+1] = q; }
  }
  __syncthreads();
  float* stf = (float*)st;
  if (tid < 96) unsafeAtomicAdd(stf + tid, bst[0][tid]+bst[1][tid]+bst[2][tid]+bst[3][tid]);
}

// ---------------- K2: spatial einsum + gsw conv -> stats; optional c2 store ----------------
// Lane = (t2, oc); wave wu handles v = wu+4i (wave-uniform). pan rows via scalar loads.
// Phase-split per j: A = compute all 7 z's + zz writes (fire-and-forget), B = read back +
// conv + stats (+ coalesced c2 store: layout [lj][n][v][t][oc] -> lane-contiguous 256B/wave).
// One lgkm drain per j instead of 7 serial write->read chains (round-6: ~470 stall cyc/iter).
__global__ __launch_bounds__(256) void k2_spatial(
    const float* __restrict__ c1, const float* __restrict__ PA,
    const float* __restrict__ gsw, const float* __restrict__ gsb,
    const float* __restrict__ gdg, const float* __restrict__ gdbt,
    float2* st, float* __restrict__ c2out, const int storec2)
{
  __shared__ float zz[4][25][16];
  __shared__ float bst[4][160];
  const int tid = threadIdx.x;
  const int l = blockIdx.z, n = blockIdx.y;
  const int wu = __builtin_amdgcn_readfirstlane(tid >> 6);
  const int lane = tid & 63;
  const int t2 = lane >> 4, oc = lane & 15;
  const int t = blockIdx.x*4 + t2;
  float cAr, cBr;
  {
    float2 s = st[l*16+oc];
    float m = s.x*(1.f/MCNT), var = s.y*(1.f/MCNT) - m*m;
    cAr = gdg[l*16+oc]*rsqrtf(var+EPSB);
    cBr = gdbt[l*16+oc] - m*cAr;
  }
  float xdr[25];
  {
    const float* c1p = c1 + ((size_t)((l*N_+n)*II + oc))*TV + t*25;
    #pragma unroll
    for (int u = 0; u < 25; u++) xdr[u] = fmaxf(cAr*c1p[u] + cBr, 0.f);
  }
  #pragma unroll 1
  for (int j = 0; j < 5; j++){
    const float* paJ = PA + (size_t)(l*5+j)*625;
    const float* gwp = gsw + ((size_t)((l*5+j)*16 + oc))*16;
    float gwr[16];
    #pragma unroll
    for (int c4 = 0; c4 < 4; c4++){
      float4 g4 = *(const float4*)(gwp + 4*c4);
      gwr[4*c4+0]=g4.x; gwr[4*c4+1]=g4.y; gwr[4*c4+2]=g4.z; gwr[4*c4+3]=g4.w;
    }
    const float bjo = gsb[(l*5+j)*16 + oc];
    // ---- phase A: all z's, zz writes only ----
    #pragma unroll
    for (int i = 0; i < 7; i++){
      const int vreal = wu + 4*i;
      const int v = vreal < 25 ? vreal : 24;
      const float* par = paJ + v*25;
      float pan[25];
      #pragma unroll
      for (int u = 0; u < 25; u++) pan[u] = par[u];
      if (vreal < 25){
        float z0 = xdr[0]*pan[0], z1 = xdr[1]*pan[1], z2 = xdr[2]*pan[2], z3 = xdr[3]*pan[3];
        #pragma unroll
        for (int u = 4; u < 24; u += 4){
          z0 += xdr[u+0]*pan[u+0];
          z1 += xdr[u+1]*pan[u+1];
          z2 += xdr[u+2]*pan[u+2];
          z3 += xdr[u+3]*pan[u+3];
        }
        z0 += xdr[24]*pan[24];
        zz[t2][v][oc] = (z0+z1)+(z2+z3);
      }
    }
    // ---- phase B: read back, conv, stats, optional store ----
    float ssum = 0.f, sq = 0.f;
    #pragma unroll
    for (int i = 0; i < 7; i++){
      const int vreal = wu + 4*i;
      if (vreal < 25){
        const float4* zr = (const float4*)&zz[t2][vreal][0];
        float4 za = zr[0], zb = zr[1], zc = zr[2], zd = zr[3];
        float d0 = gwr[0]*za.x + gwr[1]*za.y + gwr[2]*za.z + gwr[3]*za.w;
        float d1 = gwr[4]*zb.x + gwr[5]*zb.y + gwr[6]*zb.z + gwr[7]*zb.w;
        float d2 = gwr[8]*zc.x + gwr[9]*zc.y + gwr[10]*zc.z + gwr[11]*zc.w;
        float d3 = gwr[12]*zd.x + gwr[13]*zd.y + gwr[14]*zd.z + gwr[15]*zd.w;
        float cv = bjo + ((d0+d1)+(d2+d3));
        ssum += cv; sq += cv*cv;
        if (storec2){
          c2out[((((size_t)(l*5+j)*N_ + n)*25 + vreal)*T_ + t)*16 + oc] = cv;
        }
      }
    }
    ssum += __shfl_xor(ssum,16); ssum += __shfl_xor(ssum,32);
    sq   += __shfl_xor(sq,16);   sq   += __shfl_xor(sq,32);
    if (t2 == 0){ bst[wu][2*(j*16+oc)] = ssum; bst[wu][2*(j*16+oc)+1] = sq; }
  }
  __syncthreads();
  float* stf = (float*)st;
  for (int i = tid; i < 160; i += 256)
    unsafeAtomicAdd(stf + 96 + l*160 + i, bst[0][i]+bst[1][i]+bst[2][i]+bst[3][i]);
}

// ---------------- K3 (big path): read stored c2, BN, accumulate new, stats(new) ----------------
// Pure memory-bound: 1 coalesced load per (l,j,i) per lane, no LDS in hot loop.
__global__ __launch_bounds__(256) void k3_read(
    const float* __restrict__ c2, const float* __restrict__ gsg, const float* __restrict__ gsbt,
    float2* st, float* __restrict__ newb)
{
  __shared__ float cofA[15][16], cofB[15][16];
  __shared__ float bst[4][128];
  const int tid = threadIdx.x;
  const int n = blockIdx.y;
  if (tid < 240){
    int lj = tid >> 4, o = tid & 15;
    float2 s = st[48 + lj*16 + o];
    float m = s.x*(1.f/MCNT), var = s.y*(1.f/MCNT) - m*m;
    float a = gsg[lj*16+o]*rsqrtf(var+EPSB);
    cofA[lj][o] = a; cofB[lj][o] = gsbt[lj*16+o] - m*a;
  }
  __syncthreads();
  const int wu = __builtin_amdgcn_readfirstlane(tid >> 6);
  const int lane = tid & 63;
  const int t2 = lane >> 4, oc = lane & 15;
  const int t = blockIdx.x*4 + t2;
  float ac1[7], ac2[7], ac3[7], ac4[7];
  #pragma unroll
  for (int i = 0; i < 7; i++){ ac1[i]=0.f; ac2[i]=0.f; ac3[i]=0.f; ac4[i]=0.f; }
  #pragma unroll 1
  for (int l = 0; l < 3; l++){
    #pragma unroll 1
    for (int j = 0; j < 5; j++){
      const int lj = l*5 + j;
      const float a2 = cofA[lj][oc], b2 = cofB[lj][oc];
      const float* cp = c2 + (((size_t)lj*N_ + n)*25)*T_*16 + (size_t)t*16 + oc;
      float yb_[7];
      #pragma unroll
      for (int i = 0; i < 7; i++){
        const int vreal = wu + 4*i;
        yb_[i] = 0.f;
        if (vreal < 25){
          float cv = cp[(size_t)vreal*T_*16];
          yb_[i] = a2*cv + b2;
        }
      }
      if (j == 0){
        #pragma unroll
        for (int i = 0; i < 7; i++){ ac1[i]+=yb_[i]; ac2[i]+=yb_[i]; ac3[i]+=yb_[i]; ac4[i]+=yb_[i]; }
      } else if (j == 1){
        #pragma unroll
        for (int i = 0; i < 7; i++) ac1[i] += yb_[i];
      } else if (j == 2){
        #pragma unroll
        for (int i = 0; i < 7; i++) ac2[i] += yb_[i];
      } else if (j == 3){
        #pragma unroll
        for (int i = 0; i < 7; i++) ac3[i] += yb_[i];
      } else {
        #pragma unroll
        for (int i = 0; i < 7; i++) ac4[i] += yb_[i];
      }
    }
  }
  float* np = newb + (size_t)n*64*TV + t*25;
  float s0=0.f,q0=0.f,s1=0.f,q1=0.f,s2=0.f,q2=0.f,s3=0.f,q3=0.f;
  #pragma unroll
  for (int i = 0; i < 7; i++){
    const int v = wu + 4*i;
    if (v < 25){
      float v0 = ac1[i], v1 = ac2[i], v2 = ac3[i], v3 = ac4[i];
      np[(0*16+oc)*TV + v] = v0;
      np[(1*16+oc)*TV + v] = v1;
      np[(2*16+oc)*TV + v] = v2;
      np[(3*16+oc)*TV + v] = v3;
      s0 += v0; q0 += v0*v0;
      s1 += v1; q1 += v1*v1;
      s2 += v2; q2 += v2*v2;
      s3 += v3; q3 += v3*v3;
    }
  }
  s0 += __shfl_xor(s0,16); s0 += __shfl_xor(s0,32);
  q0 += __shfl_xor(q0,16); q0 += __shfl_xor(q0,32);
  s1 += __shfl_xor(s1,16); s1 += __shfl_xor(s1,32);
  q1 += __shfl_xor(q1,16); q1 += __shfl_xor(q1,32);
  s2 += __shfl_xor(s2,16); s2 += __shfl_xor(s2,32);
  q2 += __shfl_xor(q2,16); q2 += __shfl_xor(q2,32);
  s3 += __shfl_xor(s3,16); s3 += __shfl_xor(s3,32);
  q3 += __shfl_xor(q3,16); q3 += __shfl_xor(q3,32);
  if (t2 == 0){
    bst[wu][2*(0*16+oc)] = s0; bst[wu][2*(0*16+oc)+1] = q0;
    bst[wu][2*(1*16+oc)] = s1; bst[wu][2*(1*16+oc)+1] = q1;
    bst[wu][2*(2*16+oc)] = s2; bst[wu][2*(2*16+oc)+1] = q2;
    bst[wu][2*(3*16+oc)] = s3; bst[wu][2*(3*16+oc)+1] = q3;
  }
  __syncthreads();
  float* stf = (float*)st;
  for (int i = tid; i < 128; i += 256)
    unsafeAtomicAdd(stf + 576 + i, bst[0][i]+bst[1][i]+bst[2][i]+bst[3][i]);
}

// ---------------- K3 (fallback): recompute c2, BN, accumulate new, stats(new) ----------------
// Phase-split like K2; base folded into all 4 accumulators (-7 VGPR).
__global__ __launch_bounds__(256) void k3_new(
    const float* __restrict__ c1, const float* __restrict__ PA,
    const float* __restrict__ gsw, const float* __restrict__ gsb,
    const float* __restrict__ gdg, const float* __restrict__ gdbt,
    const float* __restrict__ gsg, const float* __restrict__ gsbt,
    float2* st, float* __restrict__ newb)
{
  __shared__ float zz[4][25][16];
  __shared__ float bst[4][128];
  const int tid = threadIdx.x;
  const int n = blockIdx.y;
  const int wu = __builtin_amdgcn_readfirstlane(tid >> 6);
  const int lane = tid & 63;
  const int t2 = lane >> 4, oc = lane & 15;
  const int t = blockIdx.x*4 + t2;
  float ac1[7], ac2[7], ac3[7], ac4[7];
  #pragma unroll
  for (int i = 0; i < 7; i++){ ac1[i]=0.f; ac2[i]=0.f; ac3[i]=0.f; ac4[i]=0.f; }

  #pragma unroll 1
  for (int l = 0; l < 3; l++){
    float cAr, cBr;
    {
      float2 s = st[l*16+oc];
      float m = s.x*(1.f/MCNT), var = s.y*(1.f/MCNT) - m*m;
      cAr = gdg[l*16+oc]*rsqrtf(var+EPSB);
      cBr = gdbt[l*16+oc] - m*cAr;
    }
    float xdr[25];
    {
      const float* c1p = c1 + ((size_t)((l*N_+n)*II + oc))*TV + t*25;
      #pragma unroll
      for (int u = 0; u < 25; u++) xdr[u] = fmaxf(cAr*c1p[u] + cBr, 0.f);
    }
    #pragma unroll 1
    for (int j = 0; j < 5; j++){
      const float* paJ = PA + (size_t)(l*5+j)*625;
      const float* gwp = gsw + ((size_t)((l*5+j)*16 + oc))*16;
      float gwr[16];
      #pragma unroll
      for (int c4 = 0; c4 < 4; c4++){
        float4 g4 = *(const float4*)(gwp + 4*c4);
        gwr[4*c4+0]=g4.x; gwr[4*c4+1]=g4.y; gwr[4*c4+2]=g4.z; gwr[4*c4+3]=g4.w;
      }
      const float bjo = gsb[(l*5+j)*16 + oc];
      float a2, b2;
      {
        int slot = 48 + (l*5+j)*16 + oc;
        float2 s = st[slot];
        float m = s.x*(1.f/MCNT), var = s.y*(1.f/MCNT) - m*m;
        a2 = gsg[(l*5+j)*16+oc]*rsqrtf(var+EPSB);
        b2 = gsbt[(l*5+j)*16+oc] - m*a2;
      }
      // phase A
      #pragma unroll
      for (int i = 0; i < 7; i++){
        const int vreal = wu + 4*i;
        const int v = vreal < 25 ? vreal : 24;
        const float* par = paJ + v*25;
        float pan[25];
        #pragma unroll
        for (int u = 0; u < 25; u++) pan[u] = par[u];
        if (vreal < 25){
          float z0 = xdr[0]*pan[0], z1 = xdr[1]*pan[1], z2 = xdr[2]*pan[2], z3 = xdr[3]*pan[3];
          #pragma unroll
          for (int u = 4; u < 24; u += 4){
            z0 += xdr[u+0]*pan[u+0];
            z1 += xdr[u+1]*pan[u+1];
            z2 += xdr[u+2]*pan[u+2];
            z3 += xdr[u+3]*pan[u+3];
          }
          z0 += xdr[24]*pan[24];
          zz[t2][v][oc] = (z0+z1)+(z2+z3);
        }
      }
      // phase B
      float yb_[7];
      #pragma unroll
      for (int i = 0; i < 7; i++){
        const int vreal = wu + 4*i;
        yb_[i] = 0.f;
        if (vreal < 25){
          const float4* zr = (const float4*)&zz[t2][vreal][0];
          float4 za = zr[0], zb = zr[1], zc = zr[2], zd = zr[3];
          float d0 = gwr[0]*za.x + gwr[1]*za.y + gwr[2]*za.z + gwr[3]*za.w;
          float d1 = gwr[4]*zb.x + gwr[5]*zb.y + gwr[6]*zb.z + gwr[7]*zb.w;
          float d2 = gwr[8]*zc.x + gwr[9]*zc.y + gwr[10]*zc.z + gwr[11]*zc.w;
          float d3 = gwr[12]*zd.x + gwr[13]*zd.y + gwr[14]*zd.z + gwr[15]*zd.w;
          yb_[i] = a2*(bjo + ((d0+d1)+(d2+d3))) + b2;
        }
      }
      if (j == 0){
        #pragma unroll
        for (int i = 0; i < 7; i++){ ac1[i]+=yb_[i]; ac2[i]+=yb_[i]; ac3[i]+=yb_[i]; ac4[i]+=yb_[i]; }
      } else if (j == 1){
        #pragma unroll
        for (int i = 0; i < 7; i++) ac1[i] += yb_[i];
      } else if (j == 2){
        #pragma unroll
        for (int i = 0; i < 7; i++) ac2[i] += yb_[i];
      } else if (j == 3){
        #pragma unroll
        for (int i = 0; i < 7; i++) ac3[i] += yb_[i];
      } else {
        #pragma unroll
        for (int i = 0; i < 7; i++) ac4[i] += yb_[i];
      }
    }
  }
  float* np = newb + (size_t)n*64*TV + t*25;
  float s0=0.f,q0=0.f,s1=0.f,q1=0.f,s2=0.f,q2=0.f,s3=0.f,q3=0.f;
  #pragma unroll
  for (int i = 0; i < 7; i++){
    const int v = wu + 4*i;
    if (v < 25){
      float v0 = ac1[i], v1 = ac2[i], v2 = ac3[i], v3 = ac4[i];
      np[(0*16+oc)*TV + v] = v0;
      np[(1*16+oc)*TV + v] = v1;
      np[(2*16+oc)*TV + v] = v2;
      np[(3*16+oc)*TV + v] = v3;
      s0 += v0; q0 += v0*v0;
      s1 += v1; q1 += v1*v1;
      s2 += v2; q2 += v2*v2;
      s3 += v3; q3 += v3*v3;
    }
  }
  s0 += __shfl_xor(s0,16); s0 += __shfl_xor(s0,32);
  q0 += __shfl_xor(q0,16); q0 += __shfl_xor(q0,32);
  s1 += __shfl_xor(s1,16); s1 += __shfl_xor(s1,32);
  q1 += __shfl_xor(q1,16); q1 += __shfl_xor(q1,32);
  s2 += __shfl_xor(s2,16); s2 += __shfl_xor(s2,32);
  q2 += __shfl_xor(q2,16); q2 += __shfl_xor(q2,32);
  s3 += __shfl_xor(s3,16); s3 += __shfl_xor(s3,32);
  q3 += __shfl_xor(q3,16); q3 += __shfl_xor(q3,32);
  if (t2 == 0){
    bst[wu][2*(0*16+oc)] = s0; bst[wu][2*(0*16+oc)+1] = q0;
    bst[wu][2*(1*16+oc)] = s1; bst[wu][2*(1*16+oc)+1] = q1;
    bst[wu][2*(2*16+oc)] = s2; bst[wu][2*(2*16+oc)+1] = q2;
    bst[wu][2*(3*16+oc)] = s3; bst[wu][2*(3*16+oc)+1] = q3;
  }
  __syncthreads();
  float* stf = (float*)st;
  for (int i = tid; i < 128; i += 256)
    unsafeAtomicAdd(stf + 576 + i, bst[0][i]+bst[1][i]+bst[2][i]+bst[3][i]);
}

// ---------------- K4: xg = relu(bn(new)+x); y[k] = brw[k]*xg + brb[k]; stats(y) ----------------
__global__ __launch_bounds__(256) void k4_xg_branches(
    const float* __restrict__ x, const float* __restrict__ newb,
    const float* __restrict__ gbng, const float* __restrict__ gbnb,
    const float* __restrict__ brw, const float* __restrict__ brb,
    float2* st, float* __restrict__ xg, float* __restrict__ y)
{
  __shared__ float w[64*64];     // w[c*64+ko] = brw[ko*64+c]
  __shared__ float cA[64], cB[64], bias[64];
  __shared__ float bst[4][128];
  const int tid = threadIdx.x;
  for (int i = tid; i < 4096; i += 256){ int c = i >> 6, ko = i & 63; w[i] = brw[ko*64 + c]; }
  if (tid < 64){
    float2 ab = bncoef(st, 288+tid, gbng[tid], gbnb[tid]);
    cA[tid] = ab.x; cB[tid] = ab.y; bias[tid] = brb[tid];
  }
  __syncthreads();
  const int n = blockIdx.y;
  const int rem = blockIdx.x*256 + tid;
  const bool act = rem < TV;
  const float* xp  = x    + (size_t)n*64*TV + rem;
  const float* npx = newb + (size_t)n*64*TV + rem;
  float*       xgp = xg   + (size_t)n*64*TV + rem;
  float xgv[64];
  #pragma unroll
  for (int c = 0; c < 64; c++){
    float v = 0.f;
    if (act){
      v = fmaxf(cA[c]*npx[c*TV] + cB[c] + xp[c*TV], 0.f);
      xgp[c*TV] = v;
    }
    xgv[c] = v;
  }
  const int wv = tid >> 6, lane = tid & 63;
  #pragma unroll
  for (int k = 0; k < 4; k++){
    float acc[16];
    #pragma unroll
    for (int o = 0; o < 16; o++) acc[o] = act ? bias[k*16+o] : 0.f;
    #pragma unroll
    for (int c = 0; c < 64; c++){
      float xv = xgv[c];
      const float4* w4 = (const float4*)&w[c*64 + k*16];
      #pragma unroll
      for (int o4 = 0; o4 < 4; o4++){
        float4 ww = w4[o4];
        acc[o4*4+0] += ww.x*xv; acc[o4*4+1] += ww.y*xv;
        acc[o4*4+2] += ww.z*xv; acc[o4*4+3] += ww.w*xv;
      }
    }
    if (act){
      float* yp = y + (size_t)((k*N_+n)*16)*TV + rem;
      #pragma unroll
      for (int o = 0; o < 16; o++) yp[o*TV] = acc[o];
    }
    #pragma unroll
    for (int o = 0; o < 16; o++){
      float s = acc[o], q = acc[o]*acc[o];
      #pragma unroll
      for (int m = 32; m; m >>= 1){ s += __shfl_xor(s, m); q += __shfl_xor(q, m); }
      if (lane == 0){ bst[wv][2*(k*16+o)] = s; bst[wv][2*(k*16+o)+1] = q; }
    }
  }
  __syncthreads();
  float* stf = (float*)st;
  for (int i = tid; i < 128; i += 256)
    unsafeAtomicAdd(stf + 704 + i, bst[0][i]+bst[1][i]+bst[2][i]+bst[3][i]);
}

// ---------------- K5: temporal convs (d=1,2) + maxpool branch, pre-final-BN values + stats -----
__global__ __launch_bounds__(256) void k5_temporal(
    const float* __restrict__ y, const float* __restrict__ tcw, const float* __restrict__ tcbias,
    const float* __restrict__ brg, const float* __restrict__ brbt,
    float2* st, float* __restrict__ tp)
{
  __shared__ float wt[2*16*5*16];   // [k][c][ks][o]
  __shared__ float cAy[48], cBy[48];
  __shared__ float bst[4][96];
  const int tid = threadIdx.x;
  for (int i = tid; i < 2560; i += 256){
    int k = i/1280, r = i - k*1280, c = r/80, r2 = r - c*80, ks = r2 >> 4, o = r2 & 15;
    wt[i] = tcw[((k*16+o)*16 + c)*5 + ks];
  }
  if (tid < 48){
    float2 ab = bncoef(st, 352+tid, brg[tid], brbt[tid]);
    cAy[tid] = ab.x; cBy[tid] = ab.y;
  }
  __syncthreads();
  const int n = blockIdx.y;
  const int rem = blockIdx.x*256 + tid;
  const bool act = rem < TV;
  const int t = rem/25, v = rem - t*25;
  const int wv = tid >> 6, lane = tid & 63;
  #pragma unroll
  for (int k = 0; k < 2; k++){
    const int d = k + 1;
    float acc[16];
    #pragma unroll
    for (int o = 0; o < 16; o++) acc[o] = act ? tcbias[k*16+o] : 0.f;
    if (act){
      const float* yp = y + (size_t)((k*N_+n)*16)*TV;
      #pragma unroll
      for (int ks = 0; ks < 5; ks++){
        int ttt = t + d*(ks-2);
        if (ttt >= 0 && ttt < T_){
          int off = ttt*25 + v;
          #pragma unroll
          for (int c = 0; c < 16; c++){
            float val = fmaxf(cAy[k*16+c]*yp[c*TV + off] + cBy[k*16+c], 0.f);
            const float4* w4 = (const float4*)&wt[((k*16+c)*5 + ks)*16];
            #pragma unroll
            for (int o4 = 0; o4 < 4; o4++){
              float4 ww = w4[o4];
              acc[o4*4+0] += ww.x*val; acc[o4*4+1] += ww.y*val;
              acc[o4*4+2] += ww.z*val; acc[o4*4+3] += ww.w*val;
            }
          }
        }
      }
      float* op = tp + (size_t)k*6553600 + (size_t)(n*16)*TV + rem;
      #pragma unroll
      for (int o = 0; o < 16; o++) op[o*TV] = acc[o];
    }
    #pragma unroll
    for (int o = 0; o < 16; o++){
      float s = acc[o], q = acc[o]*acc[o];
      #pragma unroll
      for (int m = 32; m; m >>= 1){ s += __shfl_xor(s, m); q += __shfl_xor(q, m); }
      if (lane == 0){ bst[wv][2*(k*16+o)] = s; bst[wv][2*(k*16+o)+1] = q; }
    }
  }
  { // maxpool branch (k=2)
    float mx[16];
    #pragma unroll
    for (int o = 0; o < 16; o++) mx[o] = -1e30f;
    if (act){
      const float* yp = y + (size_t)((2*N_+n)*16)*TV;
      #pragma unroll
      for (int dt = -1; dt <= 1; dt++){
        int ttt = t + dt;
        if (ttt >= 0 && ttt < T_){
          int off = ttt*25 + v;
          #pragma unroll
          for (int o = 0; o < 16; o++){
            float val = fmaxf(cAy[32+o]*yp[o*TV + off] + cBy[32+o], 0.f);
            mx[o] = fmaxf(mx[o], val);
          }
        }
      }
      float* op = tp + (size_t)2*6553600 + (size_t)(n*16)*TV + rem;
      #pragma unroll
      for (int o = 0; o < 16; o++) op[o*TV] = mx[o];
    } else {
      #pragma unroll
      for (int o = 0; o < 16; o++) mx[o] = 0.f;
    }
    #pragma unroll
    for (int o = 0; o < 16; o++){
      float s = mx[o], q = mx[o]*mx[o];
      #pragma unroll
      for (int m = 32; m; m >>= 1){ s += __shfl_xor(s, m); q += __shfl_xor(q, m); }
      if (lane == 0){ bst[wv][64 + 2*o] = s; bst[wv][64 + 2*o + 1] = q; }
    }
  }
  __syncthreads();
  float* stf = (float*)st;
  for (int i = tid; i < 96; i += 256)
    unsafeAtomicAdd(stf + 832 + i, bst[0][i]+bst[1][i]+bst[2][i]+bst[3][i]);
}

// ---------------- K6: final BNs + concat + residual + relu ----------------
__global__ __launch_bounds__(256) void k6_final(
    const float* __restrict__ tp, const float* __restrict__ y, const float* __restrict__ xg,
    const float* __restrict__ tcg, const float* __restrict__ tcbt,
    const float* __restrict__ mpg, const float* __restrict__ mpb,
    const float* __restrict__ brg, const float* __restrict__ brbt,
    const float2* __restrict__ st, float* __restrict__ out)
{
  __shared__ float cA[64], cB[64];
  const int tid = threadIdx.x;
  if (tid < 64){
    int o = tid & 15;
    float2 ab;
    if (tid < 32)      ab = bncoef(st, 416 + tid, tcg[tid], tcbt[tid]);
    else if (tid < 48) ab = bncoef(st, 448 + o, mpg[o], mpb[o]);
    else               ab = bncoef(st, 400 + o, brg[48+o], brbt[48+o]);
    cA[tid] = ab.x; cB[tid] = ab.y;
  }
  __syncthreads();
  const int n = blockIdx.y;
  const int rem = blockIdx.x*256 + tid;
  if (rem >= TV) return;
  const float* xgp = xg + (size_t)n*64*TV + rem;
  float* op = out + (size_t)n*64*TV + rem;
  #pragma unroll
  for (int ch = 0; ch < 64; ch++){
    int o = ch & 15;
    float sv;
    if (ch < 48) sv = tp[(size_t)(ch>>4)*6553600 + (size_t)(n*16+o)*TV + rem];
    else         sv = y[(size_t)((3*N_+n)*16 + o)*TV + rem];
    float val = cA[ch]*sv + cB[ch] + xgp[ch*TV];
    op[ch*TV] = fmaxf(val, 0.f);
  }
}

extern "C" void kernel_launch(void* const* d_in, const int* in_sizes, int n_in,
                              void* d_out, int out_size, void* d_ws, size_t ws_size,
                              hipStream_t stream) {
  (void)in_sizes; (void)n_in; (void)out_size;
  const float* x    = (const float*)d_in[0];
  const float* PA   = (const float*)d_in[1];
  const float* gdw  = (const float*)d_in[2];
  const float* gdb  = (const float*)d_in[3];
  const float* gdg  = (const float*)d_in[4];
  const float* gdbt = (const float*)d_in[5];
  const float* gsw  = (const float*)d_in[6];
  const float* gsb  = (const float*)d_in[7];
  const float* gsg  = (const float*)d_in[8];
  const float* gsbt = (const float*)d_in[9];
  const float* gbng = (const float*)d_in[10];
  const float* gbnb = (const float*)d_in[11];
  const float* brw  = (const float*)d_in[12];
  const float* brb  = (const float*)d_in[13];
  const float* brg  = (const float*)d_in[14];
  const float* brbt = (const float*)d_in[15];
  const float* tcw  = (const float*)d_in[16];
  const float* tcbias=(const float*)d_in[17];
  const float* tcg  = (const float*)d_in[18];
  const float* tcbt = (const float*)d_in[19];
  const float* mpg  = (const float*)d_in[20];
  const float* mpb  = (const float*)d_in[21];

  char* ws = (char*)d_ws;
  const size_t OFF_C1   = 4096;
  const size_t SZ_C1    = 78643200ull;     // 3*128*16*3200*4
  const size_t SZ_C2    = 393216000ull;    // 15*128*25*128*16*4
  const size_t SZ_MAP   = 104857600ull;    // 128*64*3200*4
  const size_t NEED_BIG = OFF_C1 + SZ_C1 + SZ_C2 + 3*SZ_MAP;   // 786,436,096

  const bool big = ws_size >= NEED_BIG;

  float2* st  = (float2*)ws;
  float* c1   = (float*)(ws + OFF_C1);
  float* tp   = c1;                          // c1 region reused after k3
  float* c2   = (float*)(ws + OFF_C1 + SZ_C1);   // only used when big
  float* newb, *xg, *y;
  if (big){
    newb = (float*)(ws + OFF_C1 + SZ_C1 + SZ_C2);
    xg   = (float*)(ws + OFF_C1 + SZ_C1 + SZ_C2 + SZ_MAP);
    y    = (float*)(ws + OFF_C1 + SZ_C1 + SZ_C2 + 2*SZ_MAP);
  } else {
    newb = (float*)(ws + OFF_C1 + SZ_C1);
    xg   = (float*)(ws + OFF_C1 + SZ_C1 + SZ_MAP);
    y    = (float*)(ws + OFF_C1 + SZ_C1 + 2*SZ_MAP);
  }

  hipMemsetAsync(st, 0, 4096, stream);
  dim3 b(256);
  k1_conv_dw   <<<dim3(13,128),   b, 0, stream>>>(x, gdw, gdb, c1, st);
  k2_spatial   <<<dim3(32,128,3), b, 0, stream>>>(c1, PA, gsw, gsb, gdg, gdbt, st, c2, big ? 1 : 0);
  if (big)
    k3_read    <<<dim3(32,128),   b, 0, stream>>>(c2, gsg, gsbt, st, newb);
  else
    k3_new     <<<dim3(32,128),   b, 0, stream>>>(c1, PA, gsw, gsb, gdg, gdbt, gsg, gsbt, st, newb);
  k4_xg_branches<<<dim3(13,128),  b, 0, stream>>>(x, newb, gbng, gbnb, brw, brb, st, xg, y);
  k5_temporal  <<<dim3(13,128),   b, 0, stream>>>(y, tcw, tcbias, brg, brbt, st, tp);
  k6_final     <<<dim3(13,128),   b, 0, stream>>>(tp, y, xg, tcg, tcbt, mpg, mpb, brg, brbt, st, (float*)d_out);
}